// Round 1
// baseline (307.368 us; speedup 1.0000x reference)
//
#include <hip/hip_runtime.h>
#include <hip/hip_bf16.h>
#include <hip/hip_fp16.h>

typedef _Float16 half8 __attribute__((ext_vector_type(8)));
typedef float f32x4 __attribute__((ext_vector_type(4)));
typedef float f32x2 __attribute__((ext_vector_type(2)));

// ---------------- helpers ----------------
static __device__ __forceinline__ float bf2f_lo(unsigned u) {
    return __uint_as_float(u << 16);
}
static __device__ __forceinline__ float bf2f_hi(unsigned u) {
    return __uint_as_float(u & 0xffff0000u);
}
static __device__ __forceinline__ unsigned f2bf_rne_bits(float f) {
    unsigned u = __float_as_uint(f);
    return u + 0x7fffu + ((u >> 16) & 1u);
}
static __device__ __forceinline__ unsigned pack_bf2(float a, float b) {
    return (f2bf_rne_bits(a) >> 16) | (f2bf_rne_bits(b) & 0xffff0000u);
}

// ================= CSR build: two-level bucket sort =================
#define CHUNK 4096

__global__ void kb_zero(int* bucketCount, int NBK) {
    int i = blockIdx.x * 256 + threadIdx.x;
    if (i < NBK) bucketCount[i] = 0;
}

__global__ void kb_count(const int* __restrict__ dst, int* bucketCount,
                         int E, int T, int NBK) {
    __shared__ int cnt[256];
    const int tid = threadIdx.x;
    const int beg = blockIdx.x * CHUNK;
    const int end = min(beg + CHUNK, T);
    cnt[tid] = 0;
    __syncthreads();
    for (int i = beg + tid; i < end; i += 256) {
        int d = (i < E) ? dst[i] : (i - E);
        atomicAdd(&cnt[d >> 8], 1);
    }
    __syncthreads();
    if (tid < NBK && cnt[tid] > 0) atomicAdd(&bucketCount[tid], cnt[tid]);
}

__global__ void kb_scan(const int* __restrict__ bucketCount, int* bucketBase,
                        int* bucketCursor, int* row_ptr, int NBK, int N, int total) {
    __shared__ int sm[256];
    const int tid = threadIdx.x;
    int v = (tid < NBK) ? bucketCount[tid] : 0;
    sm[tid] = v;
    __syncthreads();
    for (int off = 1; off < 256; off <<= 1) {
        int t = (tid >= off) ? sm[tid - off] : 0;
        __syncthreads();
        sm[tid] += t;
        __syncthreads();
    }
    if (tid < NBK) {
        int ex = sm[tid] - v;
        bucketBase[tid] = ex;
        bucketCursor[tid] = ex;
    }
    if (tid == 0) {
        bucketBase[NBK] = total;
        row_ptr[N] = total;
    }
}

__global__ void kb_place(const int* __restrict__ src, const int* __restrict__ dst,
                         int* bucketCursor, unsigned* __restrict__ barr,
                         int E, int T, int NBK) {
    __shared__ int cnt[256];
    __shared__ int wb[256];
    const int tid = threadIdx.x;
    const int beg = blockIdx.x * CHUNK;
    const int end = min(beg + CHUNK, T);
    cnt[tid] = 0;
    __syncthreads();
    for (int i = beg + tid; i < end; i += 256) {
        int d = (i < E) ? dst[i] : (i - E);
        atomicAdd(&cnt[d >> 8], 1);
    }
    __syncthreads();
    if (tid < NBK) {
        int c = cnt[tid];
        wb[tid] = (c > 0) ? atomicAdd(&bucketCursor[tid], c) : 0;
    }
    __syncthreads();
    cnt[tid] = 0;
    __syncthreads();
    for (int i = beg + tid; i < end; i += 256) {
        int s, d;
        if (i < E) { s = src[i]; d = dst[i]; }
        else       { s = i - E;  d = s; }
        int g = d >> 8;
        unsigned pk = (unsigned)s | ((unsigned)(d & 255) << 16);
        int r = atomicAdd(&cnt[g], 1);
        barr[wb[g] + r] = pk;
    }
}

__global__ void kb_csr(const unsigned* __restrict__ barr, const int* __restrict__ bucketBase,
                       int* __restrict__ row_ptr, int* __restrict__ col, int N) {
    __shared__ int cnt[256];
    __shared__ int sm[256];
    __shared__ int cur[256];
    const int tid = threadIdx.x;
    const int b = blockIdx.x;
    const int beg = bucketBase[b];
    const int end = bucketBase[b + 1];
    cnt[tid] = 0;
    __syncthreads();
    for (int i = beg + tid; i < end; i += 256)
        atomicAdd(&cnt[barr[i] >> 16], 1);
    __syncthreads();
    int v = cnt[tid];
    sm[tid] = v;
    __syncthreads();
    for (int off = 1; off < 256; off <<= 1) {
        int t = (tid >= off) ? sm[tid - off] : 0;
        __syncthreads();
        sm[tid] += t;
        __syncthreads();
    }
    int ex = sm[tid] - v;
    int n = b * 256 + tid;
    if (n < N) row_ptr[n] = beg + ex;
    cur[tid] = beg + ex;
    __syncthreads();
    for (int i = beg + tid; i < end; i += 256) {
        unsigned p = barr[i];
        int pos = atomicAdd(&cur[p >> 16], 1);
        col[pos] = (int)(p & 0xFFFFu);
    }
}

// ---------------- MFMA GEMM: h = A @ W (fp32 in, bf16 out) + alpha epilogue ----
// mfma_f32_16x16x32_f16 with SWAPPED operands: A-op = W^T (from LDS), B-op = x
// rows (from global). Output D[c][m]: lane holds rows m=lane&15 (as D-col) and
// 4 CONSECUTIVE cols c = ct*16 + quad*4 + reg (as D-row) -> packed bf16 stores.
// fp16 input rounding (10-bit mantissa) keeps error ~3e-4 rms (vs 4.5e-3 thr).
__launch_bounds__(256)
__global__ void k_gemm(const float* __restrict__ A, const float* __restrict__ W,
                       const float* __restrict__ a_src, const float* __restrict__ a_dst,
                       unsigned* __restrict__ Hout,
                       float* __restrict__ asrc_o, float* __restrict__ adst_o,
                       int nrows, int ntiles) {
    __shared__ _Float16 Wt[128 * 136];  // [c][k], stride 136 (272B = 16*17, b128-aligned)
    const int tid = threadIdx.x;
    // stage W^T (fp32 [k][c] -> fp16 [c][k]), coalesced global reads
    for (int idx = tid; idx < 128 * 128 / 4; idx += 256) {
        int k = idx >> 5;            // 32 float4 per k-row
        int c4 = (idx & 31) * 4;
        float4 v = *(const float4*)&W[(size_t)k * 128 + c4];
        Wt[(c4 + 0) * 136 + k] = (_Float16)v.x;
        Wt[(c4 + 1) * 136 + k] = (_Float16)v.y;
        Wt[(c4 + 2) * 136 + k] = (_Float16)v.z;
        Wt[(c4 + 3) * 136 + k] = (_Float16)v.w;
    }
    __syncthreads();
    const int lane = tid & 63;
    const int m = lane & 15, quad = lane >> 4;

    // W fragments -> registers: wf[ks][ct] = A-op[mA=lane&15][k=quad*8+j]
    half8 wf[4][8];
#pragma unroll
    for (int ks = 0; ks < 4; ++ks)
#pragma unroll
        for (int ct = 0; ct < 8; ++ct)
            wf[ks][ct] = *(half8*)&Wt[(ct * 16 + m) * 136 + ks * 32 + quad * 8];

    const int wv = (blockIdx.x * 256 + tid) >> 6;
    const int nwaves = gridDim.x * 4;
    for (int t = wv; t < ntiles; t += nwaves) {
        const int row = t * 16 + m;
        const int rc = min(row, nrows - 1);
        const float* ap = A + (size_t)rc * 128;
        f32x4 acc[8];
#pragma unroll
        for (int ct = 0; ct < 8; ++ct) acc[ct] = (f32x4){0.f, 0.f, 0.f, 0.f};
#pragma unroll
        for (int ks = 0; ks < 4; ++ks) {
            float4 x0 = *(const float4*)&ap[ks * 32 + quad * 8];
            float4 x1 = *(const float4*)&ap[ks * 32 + quad * 8 + 4];
            half8 af;
            af[0] = (_Float16)x0.x; af[1] = (_Float16)x0.y;
            af[2] = (_Float16)x0.z; af[3] = (_Float16)x0.w;
            af[4] = (_Float16)x1.x; af[5] = (_Float16)x1.y;
            af[6] = (_Float16)x1.z; af[7] = (_Float16)x1.w;
#pragma unroll
            for (int ct = 0; ct < 8; ++ct)
                acc[ct] = __builtin_amdgcn_mfma_f32_16x16x32_f16(wf[ks][ct], af, acc[ct], 0, 0, 0);
        }
        // h store: lane's 4 consecutive cols per ct -> 2 packed uints
        if (row < nrows) {
#pragma unroll
            for (int ct = 0; ct < 8; ++ct) {
                uint2 o;
                o.x = pack_bf2(acc[ct][0], acc[ct][1]);
                o.y = pack_bf2(acc[ct][2], acc[ct][3]);
                *(uint2*)&Hout[(size_t)row * 64 + ct * 8 + quad * 2] = o;
            }
        }
        // alpha partials (fp32, pre-rounding); a_src/a_dst are L1-hot (512B)
        float ps[4] = {0.f, 0.f, 0.f, 0.f}, pd[4] = {0.f, 0.f, 0.f, 0.f};
#pragma unroll
        for (int ct = 0; ct < 8; ++ct) {
            int hh = ct >> 1;
#pragma unroll
            for (int r = 0; r < 4; ++r) {
                int c = ct * 16 + quad * 4 + r;
                ps[hh] += acc[ct][r] * a_src[c];
                pd[hh] += acc[ct][r] * a_dst[c];
            }
        }
#pragma unroll
        for (int hh = 0; hh < 4; ++hh) {
            ps[hh] += __shfl_xor(ps[hh], 16); ps[hh] += __shfl_xor(ps[hh], 32);
            pd[hh] += __shfl_xor(pd[hh], 16); pd[hh] += __shfl_xor(pd[hh], 32);
        }
        if (row < nrows) {
            asrc_o[(size_t)row * 4 + quad] = ps[quad];
            adst_o[(size_t)row * 4 + quad] = pd[quad];
        }
    }
}

// ---------------- fused softmax-aggregate + bias + ELU (R6: x4 gathers) -------
// Wave = 1 dst node. Two lane decompositions:
//   p-compute:  eb = lane>>2 (16 edges/batch), hp = lane&3 (head)
//   h-gather:   q  = lane>>4 (edge sub-slot),  sl = lane&15 (16B chunk of row)
// Per batch of 16 edges: p is computed per (eb,hp) lane, packed into one word
// {src:16 | p_f16:16}; ONE ds_bpermute per 4 edges serves both gather address
// and weight. Gathers are dwordx4 (4 edges per VMEM instr). asrc gather and
// col are prefetched one batch ahead. Accumulation fp32 (float2 -> pk_fma).
#define BAT 16
__launch_bounds__(256)
__global__ void k_aggr(const unsigned* __restrict__ h,
                       const float* __restrict__ asrc, const float* __restrict__ adst,
                       const float* __restrict__ bias,
                       const int* __restrict__ row_ptr, const int* __restrict__ col,
                       float* __restrict__ out, int N) {
    const int lane = threadIdx.x & 63;
    const int d = blockIdx.x * 4 + (threadIdx.x >> 6);
    if (d >= N) return;
    const int eb = lane >> 2;
    const int hp = lane & 3;
    const int q  = lane >> 4;          // edge sub-slot within group of 4
    const int sl = lane & 15;          // 16B chunk within 256B row
    const int hs = sl >> 2;            // head owning this lane's 8 channels
    const int bidx = q * 4 + hs;       // bpermute source lane (k=0)

    const float adv = adst[(size_t)d * 4 + hp];
    const int beg = row_ptr[d];
    const int end = row_ptr[d + 1];

    f32x2 acc[4];
#pragma unroll
    for (int i = 0; i < 4; ++i) acc[i] = (f32x2){0.f, 0.f};
    float sp = 0.f;

    int cv = 0;
    { int idx = beg + eb; if (idx < end) cv = col[idx]; }
    float av = asrc[(size_t)(unsigned)cv * 4 + hp];

    for (int j = beg; j < end; j += BAT) {
        // prefetch next batch's col + asrc (hides their latency under gathers)
        int cvn = 0;
        { int idx = j + BAT + eb; if (idx < end) cvn = col[idx]; }
        float avn = asrc[(size_t)(unsigned)cvn * 4 + hp];

        // p for current batch (per (eb,hp) lane); |e| small -> no max-sub
        float e = av + adv;
        e = fmaxf(e, 0.2f * e);
        float p = (j + eb < end) ? __expf(e) : 0.f;
        unsigned hb = (unsigned)__half_as_ushort(__float2half(p));
        sp += __half2float(__ushort_as_half((unsigned short)hb)); // f16-consistent norm
        unsigned w = (unsigned)(unsigned short)cv | (hb << 16);

        // one bpermute per 4 edges: {src, p} for edge (4k+q), head hs
        unsigned wq[4];
#pragma unroll
        for (int k = 0; k < 4; ++k) wq[k] = (unsigned)__shfl((int)w, bidx + 16 * k);

        // 4 dwordx4 gathers: 16 lanes cover one 256B row -> 4 edges per instr
        uint4 u[4];
#pragma unroll
        for (int k = 0; k < 4; ++k) {
            unsigned sv = wq[k] & 0xffffu;
            u[k] = *(const uint4*)&h[(size_t)sv * 64 + sl * 4];
        }
#pragma unroll
        for (int k = 0; k < 4; ++k) {
            float pf = __half2float(__ushort_as_half((unsigned short)(wq[k] >> 16)));
            f32x2 pv = {pf, pf};
            f32x2 h0 = {bf2f_lo(u[k].x), bf2f_hi(u[k].x)};
            f32x2 h1 = {bf2f_lo(u[k].y), bf2f_hi(u[k].y)};
            f32x2 h2 = {bf2f_lo(u[k].z), bf2f_hi(u[k].z)};
            f32x2 h3 = {bf2f_lo(u[k].w), bf2f_hi(u[k].w)};
            acc[0] = __builtin_elementwise_fma(h0, pv, acc[0]);
            acc[1] = __builtin_elementwise_fma(h1, pv, acc[1]);
            acc[2] = __builtin_elementwise_fma(h2, pv, acc[2]);
            acc[3] = __builtin_elementwise_fma(h3, pv, acc[3]);
        }
        cv = cvn; av = avn;
    }

    // combine the 4 q-subsets (lanes differing in bits 4,5 hold same channels)
#pragma unroll
    for (int i = 0; i < 4; ++i) {
#pragma unroll
        for (int c = 0; c < 2; ++c) {
            acc[i][c] += __shfl_xor(acc[i][c], 16);
            acc[i][c] += __shfl_xor(acc[i][c], 32);
        }
    }
    // softmax denom per head: reduce p over eb; lane L then holds s[L&3]
    sp += __shfl_xor(sp, 4);
    sp += __shfl_xor(sp, 8);
    sp += __shfl_xor(sp, 16);
    sp += __shfl_xor(sp, 32);
    float s = __shfl(sp, hs);
    float inv = 1.f / s;

    // lane writes channels c = 8*sl + 2*q (+0,1) = acc[q]; static select (no scratch)
    float a0 = (q == 0) ? acc[0][0] : (q == 1) ? acc[1][0] : (q == 2) ? acc[2][0] : acc[3][0];
    float a1 = (q == 0) ? acc[0][1] : (q == 1) ? acc[1][1] : (q == 2) ? acc[2][1] : acc[3][1];
    int c = sl * 8 + q * 2;
    float v0 = a0 * inv + bias[c];
    float v1 = a1 * inv + bias[c + 1];
    v0 = (v0 > 0.f) ? v0 : (__expf(v0) - 1.f);
    v1 = (v1 > 0.f) ? v1 : (__expf(v1) - 1.f);
    *(float2*)&out[(size_t)d * 128 + c] = make_float2(v0, v1);
}

// ---------------- launch ----------------
extern "C" void kernel_launch(void* const* d_in, const int* in_sizes, int n_in,
                              void* d_out, int out_size, void* d_ws, size_t ws_size,
                              hipStream_t stream) {
    const float* x      = (const float*)d_in[0];
    const int*   ei     = (const int*)d_in[1];
    const float* W1     = (const float*)d_in[2];
    const float* a_src1 = (const float*)d_in[3];
    const float* a_dst1 = (const float*)d_in[4];
    const float* b1     = (const float*)d_in[5];
    const float* W2     = (const float*)d_in[6];
    const float* a_src2 = (const float*)d_in[7];
    const float* a_dst2 = (const float*)d_in[8];
    const float* b2     = (const float*)d_in[9];

    const int N = in_sizes[0] / 128;
    const int E = in_sizes[1] / 2;
    const int T = E + N;
    const int NBK = (N + 255) / 256;
    const int* src = ei;
    const int* dst = ei + E;

    char* w = (char*)d_ws;
    auto alloc = [&](size_t bytes) -> char* {
        char* p = w;
        w += (bytes + 255) & ~(size_t)255;
        return p;
    };
    unsigned* h_bf    = (unsigned*)alloc((size_t)N * 64 * 4);
    float*    o1      = (float*)alloc((size_t)N * 128 * 4);
    float*    asrc    = (float*)alloc((size_t)N * 4 * 4);
    float*    adst    = (float*)alloc((size_t)N * 4 * 4);
    int*      row_ptr = (int*)alloc((size_t)(N + 1) * 4);
    int*      col     = (int*)alloc((size_t)T * 4);
    int*      bCount  = (int*)alloc((size_t)NBK * 4);
    int*      bBase   = (int*)alloc((size_t)(NBK + 1) * 4);
    int*      bCursor = (int*)alloc((size_t)NBK * 4);
    unsigned* barr    = (unsigned*)o1;   // alias: dead before o1 written
    (void)ws_size; (void)n_in; (void)out_size;

    const int PB = (T + CHUNK - 1) / CHUNK;

    hipLaunchKernelGGL(kb_zero, dim3((NBK + 255) / 256), dim3(256), 0, stream, bCount, NBK);
    hipLaunchKernelGGL(kb_count, dim3(PB), dim3(256), 0, stream, dst, bCount, E, T, NBK);
    hipLaunchKernelGGL(kb_scan, dim3(1), dim3(256), 0, stream, bCount, bBase, bCursor, row_ptr, NBK, N, T);
    hipLaunchKernelGGL(kb_place, dim3(PB), dim3(256), 0, stream, src, dst, bCursor, barr, E, T, NBK);
    hipLaunchKernelGGL(kb_csr, dim3(NBK), dim3(256), 0, stream, barr, bBase, row_ptr, col, N);

    const int ntiles = (N + 15) / 16;
    const int GB = 512;               // grid-stride over tiles (2048 waves)
    const int AB = (N + 3) / 4;

    hipLaunchKernelGGL(k_gemm, dim3(GB), dim3(256), 0, stream, x, W1, a_src1, a_dst1, h_bf, asrc, adst, N, ntiles);
    hipLaunchKernelGGL(k_aggr, dim3(AB), dim3(256), 0, stream, h_bf, asrc, adst, b1, row_ptr, col, o1, N);
    hipLaunchKernelGGL(k_gemm, dim3(GB), dim3(256), 0, stream, o1, W2, a_src2, a_dst2, h_bf, asrc, adst, N, ntiles);
    hipLaunchKernelGGL(k_aggr, dim3(AB), dim3(256), 0, stream, h_bf, asrc, adst, b2, row_ptr, col, (float*)d_out, N);
}